// Round 1
// baseline (1654.561 us; speedup 1.0000x reference)
//
#include <hip/hip_runtime.h>
#include <math.h>

#define NN 2048
#define HH 64

// ---------- layer 0: x0 = relu((adj @ nf) @ W0 + b0), nf is (N,4) ----------
__global__ __launch_bounds__(256) void gcn0_kernel(const float* __restrict__ adj,
                                                   const float* __restrict__ nf,
                                                   const float* __restrict__ W0,
                                                   const float* __restrict__ b0,
                                                   float* __restrict__ xout) {
  int w = threadIdx.x >> 6;        // wave 0..3 -> row
  int l = threadIdx.x & 63;        // lane
  int i = blockIdx.x * 4 + w;
  const float* arow = adj + (size_t)i * NN;
  double s0 = 0, s1 = 0, s2 = 0, s3 = 0;
  for (int k = l; k < NN; k += 64) {
    float a = arow[k];
    float4 v = *(const float4*)(nf + (size_t)k * 4);
    s0 += (double)a * (double)v.x;
    s1 += (double)a * (double)v.y;
    s2 += (double)a * (double)v.z;
    s3 += (double)a * (double)v.w;
  }
  #pragma unroll
  for (int m = 32; m >= 1; m >>= 1) {
    s0 += __shfl_xor(s0, m, 64);
    s1 += __shfl_xor(s1, m, 64);
    s2 += __shfl_xor(s2, m, 64);
    s3 += __shfl_xor(s3, m, 64);
  }
  double y = (double)b0[l];
  y += s0 * (double)W0[0 * HH + l];
  y += s1 * (double)W0[1 * HH + l];
  y += s2 * (double)W0[2 * HH + l];
  y += s3 * (double)W0[3 * HH + l];
  float r = (float)y;
  xout[(size_t)i * HH + l] = r > 0.f ? r : 0.f;
}

// ---------- layers 1,2: xout = relu((adj @ xin) @ W + b), xin is (N,64) ----------
#define KT 128
__global__ __launch_bounds__(256) void gcnL_kernel(const float* __restrict__ adj,
                                                   const float* __restrict__ xin,
                                                   const float* __restrict__ W,
                                                   const float* __restrict__ b,
                                                   float* __restrict__ xout) {
  __shared__ float xs[KT][HH];       // 32 KB
  __shared__ float adjs[4][KT];      // 2 KB
  __shared__ double sred[4][HH];     // 2 KB
  int tid = threadIdx.x;
  int w = tid >> 6, l = tid & 63;    // wave -> row, lane -> column
  int i0 = blockIdx.x * 4;
  double acc = 0.0;
  for (int k0 = 0; k0 < NN; k0 += KT) {
    __syncthreads();
    const float4* xsrc = (const float4*)(xin + (size_t)k0 * HH);
    float4* xdst = (float4*)&xs[0][0];
    for (int idx = tid; idx < KT * HH / 4; idx += 256) xdst[idx] = xsrc[idx];
    for (int idx = tid; idx < 4 * KT / 4; idx += 256) {
      int r = idx >> 5, c4 = idx & 31;
      *(float4*)&adjs[r][c4 * 4] =
          *(const float4*)(adj + (size_t)(i0 + r) * NN + k0 + c4 * 4);
    }
    __syncthreads();
    #pragma unroll 8
    for (int kk = 0; kk < KT; ++kk) {
      acc += (double)adjs[w][kk] * (double)xs[kk][l];
    }
  }
  sred[w][l] = acc;
  __syncthreads();
  double y = (double)b[l];
  #pragma unroll 8
  for (int d = 0; d < HH; ++d) y += sred[w][d] * (double)W[d * HH + l];
  float r = (float)y;
  xout[(size_t)(i0 + w) * HH + l] = r > 0.f ? r : 0.f;
}

// ---------- A = x2 @ We1[0:64,:] + be1 ; B = x2 @ We1[64:128,:] ----------
__global__ __launch_bounds__(128) void ab_kernel(const float* __restrict__ x2,
                                                 const float* __restrict__ We1,
                                                 const float* __restrict__ be1,
                                                 float* __restrict__ A,
                                                 float* __restrict__ B) {
  int i = blockIdx.x;
  int c = threadIdx.x;               // 0..127
  __shared__ float xrow[HH];
  if (threadIdx.x < HH) xrow[threadIdx.x] = x2[(size_t)i * HH + threadIdx.x];
  __syncthreads();
  float accA = be1[c], accB = 0.f;
  #pragma unroll 8
  for (int d = 0; d < HH; ++d) {
    float xv = xrow[d];
    accA = fmaf(xv, We1[d * 128 + c], accA);
    accB = fmaf(xv, We1[(HH + d) * 128 + c], accB);
  }
  A[(size_t)i * 128 + c] = accA;
  B[(size_t)i * 128 + c] = accB;
}

// ---------- pair MLP: out[pair(i,j)] = sigmoid(relu(relu(A_i+B_j)@We2+be2)@We3+be3) ----------
__global__ __launch_bounds__(512, 4) void pair_kernel(const float* __restrict__ A,
                                                      const float* __restrict__ B,
                                                      const float* __restrict__ We2,
                                                      const float* __restrict__ be2,
                                                      const float* __restrict__ We3,
                                                      const float* __restrict__ be3,
                                                      float* __restrict__ out) {
  int j0 = blockIdx.x * 64;
  int i0 = blockIdx.y * 8;
  if (j0 + 63 <= i0) return;         // whole tile below diagonal
  __shared__ float We2s[128 * 64];   // 32 KB, row-major [c1][c2]
  __shared__ float Bs[64 * 132];     // 33 KB, padded stride vs bank stride-128 pathology
  __shared__ float As[8 * 128];      // 4 KB
  __shared__ float be2s[64];
  __shared__ float We3s[64];
  int tid = threadIdx.x;
  {
    const float4* s = (const float4*)We2;
    float4* d = (float4*)We2s;
    #pragma unroll
    for (int t = 0; t < 4; ++t) d[tid + t * 512] = s[tid + t * 512];
    #pragma unroll
    for (int t = 0; t < 4; ++t) {
      int idx = tid + t * 512;       // 0..2047
      int r = idx >> 5, c4 = idx & 31;
      *(float4*)&Bs[r * 132 + c4 * 4] =
          *(const float4*)(B + (size_t)(j0 + r) * 128 + c4 * 4);
    }
    if (tid < 256) ((float4*)As)[tid] = *(const float4*)(A + (size_t)i0 * 128 + tid * 4);
    if (tid < 64) { be2s[tid] = be2[tid]; We3s[tid] = We3[tid]; }
  }
  __syncthreads();
  int w = tid >> 6, l = tid & 63;
  int i = i0 + w, j = j0 + l;
  float acc[64];
  #pragma unroll
  for (int c = 0; c < 64; ++c) acc[c] = be2s[c];
  const float* Ar = &As[w * 128];
  const float* Br = &Bs[l * 132];
  #pragma unroll 2
  for (int q = 0; q < 32; ++q) {
    float4 a4 = *(const float4*)(Ar + q * 4);
    float4 b4 = *(const float4*)(Br + q * 4);
    float h0 = a4.x + b4.x; h0 = h0 > 0.f ? h0 : 0.f;
    float h1 = a4.y + b4.y; h1 = h1 > 0.f ? h1 : 0.f;
    float h2 = a4.z + b4.z; h2 = h2 > 0.f ? h2 : 0.f;
    float h3 = a4.w + b4.w; h3 = h3 > 0.f ? h3 : 0.f;
    const float* wr = We2s + q * 4 * 64;
    #pragma unroll
    for (int c2q = 0; c2q < 16; ++c2q) {
      float4 w0 = *(const float4*)(wr + c2q * 4);
      float4 w1 = *(const float4*)(wr + 64 + c2q * 4);
      float4 w2 = *(const float4*)(wr + 128 + c2q * 4);
      float4 w3 = *(const float4*)(wr + 192 + c2q * 4);
      float* a = acc + c2q * 4;
      a[0] = fmaf(h3, w3.x, fmaf(h2, w2.x, fmaf(h1, w1.x, fmaf(h0, w0.x, a[0]))));
      a[1] = fmaf(h3, w3.y, fmaf(h2, w2.y, fmaf(h1, w1.y, fmaf(h0, w0.y, a[1]))));
      a[2] = fmaf(h3, w3.z, fmaf(h2, w2.z, fmaf(h1, w1.z, fmaf(h0, w0.z, a[2]))));
      a[3] = fmaf(h3, w3.w, fmaf(h2, w2.w, fmaf(h1, w1.w, fmaf(h0, w0.w, a[3]))));
    }
  }
  float logit = be3[0];
  #pragma unroll
  for (int c = 0; c < 64; ++c) {
    float h = acc[c] > 0.f ? acc[c] : 0.f;
    logit = fmaf(h, We3s[c], logit);
  }
  float prob = 1.0f / (1.0f + expf(-logit));
  if (j > i) {
    int idx = i * (NN - 1) - (i * (i - 1)) / 2 + (j - i - 1);
    out[idx] = prob;
  }
}

extern "C" void kernel_launch(void* const* d_in, const int* in_sizes, int n_in,
                              void* d_out, int out_size, void* d_ws, size_t ws_size,
                              hipStream_t stream) {
  (void)in_sizes; (void)n_in; (void)out_size; (void)ws_size;
  const float* nf  = (const float*)d_in[0];
  const float* adj = (const float*)d_in[1];
  const float* W0  = (const float*)d_in[2];
  const float* b0  = (const float*)d_in[3];
  const float* W1  = (const float*)d_in[4];
  const float* b1  = (const float*)d_in[5];
  const float* W2  = (const float*)d_in[6];
  const float* b2  = (const float*)d_in[7];
  const float* We1 = (const float*)d_in[8];
  const float* be1 = (const float*)d_in[9];
  const float* We2 = (const float*)d_in[10];
  const float* be2 = (const float*)d_in[11];
  const float* We3 = (const float*)d_in[12];
  const float* be3 = (const float*)d_in[13];
  float* out = (float*)d_out;

  char* ws = (char*)d_ws;
  float* x0 = (float*)(ws);                       // 512 KB
  float* x1 = (float*)(ws + (512 << 10));         // 512 KB
  float* x2 = (float*)(ws + (1024 << 10));        // 512 KB
  float* Ab = (float*)(ws + (1536 << 10));        // 1 MB
  float* Bb = (float*)(ws + (2560 << 10));        // 1 MB

  gcn0_kernel<<<NN / 4, 256, 0, stream>>>(adj, nf, W0, b0, x0);
  gcnL_kernel<<<NN / 4, 256, 0, stream>>>(adj, x0, W1, b1, x1);
  gcnL_kernel<<<NN / 4, 256, 0, stream>>>(adj, x1, W2, b2, x2);
  ab_kernel<<<NN, 128, 0, stream>>>(x2, We1, be1, Ab, Bb);
  pair_kernel<<<dim3(NN / 64, NN / 8), 512, 0, stream>>>(Ab, Bb, We2, be2, We3, be3, out);
}

// Round 2
// 886.837 us; speedup vs baseline: 1.8657x; 1.8657x over previous
//
#include <hip/hip_runtime.h>
#include <math.h>

#define NN 2048
#define HH 64

// ---------- layer 0: x0 = relu((adj @ nf) @ W0 + b0), nf is (N,4) ----------
__global__ __launch_bounds__(256) void gcn0_kernel(const float* __restrict__ adj,
                                                   const float* __restrict__ nf,
                                                   const float* __restrict__ W0,
                                                   const float* __restrict__ b0,
                                                   float* __restrict__ xout) {
  int w = threadIdx.x >> 6;        // wave 0..3 -> row
  int l = threadIdx.x & 63;        // lane
  int i = blockIdx.x * 4 + w;
  const float* arow = adj + (size_t)i * NN;
  double s0 = 0, s1 = 0, s2 = 0, s3 = 0;
  for (int k = l; k < NN; k += 64) {
    float a = arow[k];
    float4 v = *(const float4*)(nf + (size_t)k * 4);
    s0 += (double)a * (double)v.x;
    s1 += (double)a * (double)v.y;
    s2 += (double)a * (double)v.z;
    s3 += (double)a * (double)v.w;
  }
  #pragma unroll
  for (int m = 32; m >= 1; m >>= 1) {
    s0 += __shfl_xor(s0, m, 64);
    s1 += __shfl_xor(s1, m, 64);
    s2 += __shfl_xor(s2, m, 64);
    s3 += __shfl_xor(s3, m, 64);
  }
  double y = (double)b0[l];
  y += s0 * (double)W0[0 * HH + l];
  y += s1 * (double)W0[1 * HH + l];
  y += s2 * (double)W0[2 * HH + l];
  y += s3 * (double)W0[3 * HH + l];
  float r = (float)y;
  xout[(size_t)i * HH + l] = r > 0.f ? r : 0.f;
}

// ---------- layers 1,2: xout = relu((adj @ xin) @ W + b), xin is (N,64) ----------
#define KT 128
__global__ __launch_bounds__(256) void gcnL_kernel(const float* __restrict__ adj,
                                                   const float* __restrict__ xin,
                                                   const float* __restrict__ W,
                                                   const float* __restrict__ b,
                                                   float* __restrict__ xout) {
  __shared__ float xs[KT][HH];       // 32 KB
  __shared__ float adjs[4][KT];      // 2 KB
  __shared__ double sred[4][HH];     // 2 KB
  int tid = threadIdx.x;
  int w = tid >> 6, l = tid & 63;    // wave -> row, lane -> column
  int i0 = blockIdx.x * 4;
  double acc = 0.0;
  for (int k0 = 0; k0 < NN; k0 += KT) {
    __syncthreads();
    const float4* xsrc = (const float4*)(xin + (size_t)k0 * HH);
    float4* xdst = (float4*)&xs[0][0];
    for (int idx = tid; idx < KT * HH / 4; idx += 256) xdst[idx] = xsrc[idx];
    for (int idx = tid; idx < 4 * KT / 4; idx += 256) {
      int r = idx >> 5, c4 = idx & 31;
      *(float4*)&adjs[r][c4 * 4] =
          *(const float4*)(adj + (size_t)(i0 + r) * NN + k0 + c4 * 4);
    }
    __syncthreads();
    #pragma unroll 8
    for (int kk = 0; kk < KT; ++kk) {
      acc += (double)adjs[w][kk] * (double)xs[kk][l];
    }
  }
  sred[w][l] = acc;
  __syncthreads();
  double y = (double)b[l];
  #pragma unroll 8
  for (int d = 0; d < HH; ++d) y += sred[w][d] * (double)W[d * HH + l];
  float r = (float)y;
  xout[(size_t)(i0 + w) * HH + l] = r > 0.f ? r : 0.f;
}

// ---------- A = x2 @ We1[0:64,:] + be1 ; B = x2 @ We1[64:128,:] ----------
__global__ __launch_bounds__(128) void ab_kernel(const float* __restrict__ x2,
                                                 const float* __restrict__ We1,
                                                 const float* __restrict__ be1,
                                                 float* __restrict__ A,
                                                 float* __restrict__ B) {
  int i = blockIdx.x;
  int c = threadIdx.x;               // 0..127
  __shared__ float xrow[HH];
  if (threadIdx.x < HH) xrow[threadIdx.x] = x2[(size_t)i * HH + threadIdx.x];
  __syncthreads();
  float accA = be1[c], accB = 0.f;
  #pragma unroll 8
  for (int d = 0; d < HH; ++d) {
    float xv = xrow[d];
    accA = fmaf(xv, We1[d * 128 + c], accA);
    accB = fmaf(xv, We1[(HH + d) * 128 + c], accB);
  }
  A[(size_t)i * 128 + c] = accA;
  B[(size_t)i * 128 + c] = accB;
}

// ---------- pair MLP: register-blocked fp32 GEMM, fused h1 = relu(A_i + B_j) ----------
// Block: 8 i-rows x 64 j-cols x 64 c2. 512 threads; thread = (r = tid>>3, c = tid&7)
// owns pairs (i = i0 + (r>>3), j = j0 + (r&7)*8 .. +7) and c2 = c*8 .. +7.
#define BTP 68  // Bt row pad (floats): keeps 16B alignment, breaks bank pathology
__global__ __launch_bounds__(512, 4) void pair_kernel(const float* __restrict__ A,
                                                      const float* __restrict__ B,
                                                      const float* __restrict__ We2,
                                                      const float* __restrict__ be2,
                                                      const float* __restrict__ We3,
                                                      const float* __restrict__ be3,
                                                      float* __restrict__ out) {
  int j0 = blockIdx.x * 64;
  int i0 = blockIdx.y * 8;
  if (j0 + 63 <= i0) return;         // tile entirely below/on diagonal
  __shared__ float We2s[128 * 64];   // 32 KB  [k][c2]
  __shared__ float Bt[128 * BTP];    // 34 KB  [k][j] (transposed)
  __shared__ float As[8 * 128];      // 4 KB   [i][k]
  __shared__ float be2s[64];
  __shared__ float We3s[64];
  int tid = threadIdx.x;
  {
    const float4* s = (const float4*)We2;
    float4* d = (float4*)We2s;
    #pragma unroll
    for (int it = 0; it < 4; ++it) d[tid + it * 512] = s[tid + it * 512];
  }
  if (tid < 256) {
    int ir = tid >> 5, kc = tid & 31;
    *(float4*)&As[ir * 128 + kc * 4] =
        *(const float4*)(A + (size_t)(i0 + ir) * 128 + kc * 4);
  }
  #pragma unroll
  for (int it = 0; it < 4; ++it) {
    int idx = tid + it * 512;        // 0..2047
    int kc = idx & 31, j = idx >> 5; // coalesced global read of B row
    float4 gb = *(const float4*)(B + (size_t)(j0 + j) * 128 + kc * 4);
    Bt[(kc * 4 + 0) * BTP + j] = gb.x;
    Bt[(kc * 4 + 1) * BTP + j] = gb.y;
    Bt[(kc * 4 + 2) * BTP + j] = gb.z;
    Bt[(kc * 4 + 3) * BTP + j] = gb.w;
  }
  if (tid < 64) { be2s[tid] = be2[tid]; We3s[tid] = We3[tid]; }
  __syncthreads();

  int c = tid & 7;                   // c2 chunk
  int r = tid >> 3;                  // 0..63
  int ir = r >> 3;                   // i within tile
  int jc = r & 7;                    // j chunk
  int i = i0 + ir;
  int jb = j0 + jc * 8;
  int c8 = c * 8;
  int jc8 = jc * 8;

  float acc[8][8];
  #pragma unroll
  for (int m = 0; m < 8; ++m) {
    #pragma unroll
    for (int n = 0; n < 8; ++n) acc[m][n] = be2s[c8 + n];
  }

  const float* Arow = &As[ir * 128];
  #pragma unroll 2
  for (int kk = 0; kk < 128; ++kk) {
    float a = Arow[kk];
    float4 bA = *(const float4*)&Bt[kk * BTP + jc8];
    float4 bB = *(const float4*)&Bt[kk * BTP + jc8 + 4];
    float4 wA = *(const float4*)&We2s[kk * 64 + c8];
    float4 wB = *(const float4*)&We2s[kk * 64 + c8 + 4];
    float h0 = fmaxf(a + bA.x, 0.f);
    float h1 = fmaxf(a + bA.y, 0.f);
    float h2 = fmaxf(a + bA.z, 0.f);
    float h3 = fmaxf(a + bA.w, 0.f);
    float h4 = fmaxf(a + bB.x, 0.f);
    float h5 = fmaxf(a + bB.y, 0.f);
    float h6 = fmaxf(a + bB.z, 0.f);
    float h7 = fmaxf(a + bB.w, 0.f);
#define PK_ROW(m, hm)                                   \
    acc[m][0] = fmaf(hm, wA.x, acc[m][0]);              \
    acc[m][1] = fmaf(hm, wA.y, acc[m][1]);              \
    acc[m][2] = fmaf(hm, wA.z, acc[m][2]);              \
    acc[m][3] = fmaf(hm, wA.w, acc[m][3]);              \
    acc[m][4] = fmaf(hm, wB.x, acc[m][4]);              \
    acc[m][5] = fmaf(hm, wB.y, acc[m][5]);              \
    acc[m][6] = fmaf(hm, wB.z, acc[m][6]);              \
    acc[m][7] = fmaf(hm, wB.w, acc[m][7]);
    PK_ROW(0, h0) PK_ROW(1, h1) PK_ROW(2, h2) PK_ROW(3, h3)
    PK_ROW(4, h4) PK_ROW(5, h5) PK_ROW(6, h6) PK_ROW(7, h7)
#undef PK_ROW
  }

  // epilogue: h2 = relu(acc); partial dot with We3 over this thread's 8 c2
  float part[8];
  #pragma unroll
  for (int m = 0; m < 8; ++m) {
    float s = 0.f;
    #pragma unroll
    for (int n = 0; n < 8; ++n)
      s = fmaf(fmaxf(acc[m][n], 0.f), We3s[c8 + n], s);
    part[m] = s;
  }
  // reduce across the 8 c-threads (lanes differing in bits 0..2)
  #pragma unroll
  for (int m = 0; m < 8; ++m) {
    part[m] += __shfl_xor(part[m], 1, 64);
    part[m] += __shfl_xor(part[m], 2, 64);
    part[m] += __shfl_xor(part[m], 4, 64);
  }
  if (c == 0) {
    float bias = be3[0];
    #pragma unroll
    for (int m = 0; m < 8; ++m) {
      int j = jb + m;
      if (j > i) {
        float logit = part[m] + bias;
        float prob = 1.0f / (1.0f + expf(-logit));
        int idx = i * (NN - 1) - (i * (i - 1)) / 2 + (j - i - 1);
        out[idx] = prob;
      }
    }
  }
}

extern "C" void kernel_launch(void* const* d_in, const int* in_sizes, int n_in,
                              void* d_out, int out_size, void* d_ws, size_t ws_size,
                              hipStream_t stream) {
  (void)in_sizes; (void)n_in; (void)out_size; (void)ws_size;
  const float* nf  = (const float*)d_in[0];
  const float* adj = (const float*)d_in[1];
  const float* W0  = (const float*)d_in[2];
  const float* b0  = (const float*)d_in[3];
  const float* W1  = (const float*)d_in[4];
  const float* b1  = (const float*)d_in[5];
  const float* W2  = (const float*)d_in[6];
  const float* b2  = (const float*)d_in[7];
  const float* We1 = (const float*)d_in[8];
  const float* be1 = (const float*)d_in[9];
  const float* We2 = (const float*)d_in[10];
  const float* be2 = (const float*)d_in[11];
  const float* We3 = (const float*)d_in[12];
  const float* be3 = (const float*)d_in[13];
  float* out = (float*)d_out;

  char* ws = (char*)d_ws;
  float* x0 = (float*)(ws);                       // 512 KB
  float* x1 = (float*)(ws + (512 << 10));         // 512 KB
  float* x2 = (float*)(ws + (1024 << 10));        // 512 KB
  float* Ab = (float*)(ws + (1536 << 10));        // 1 MB
  float* Bb = (float*)(ws + (2560 << 10));        // 1 MB

  gcn0_kernel<<<NN / 4, 256, 0, stream>>>(adj, nf, W0, b0, x0);
  gcnL_kernel<<<NN / 4, 256, 0, stream>>>(adj, x0, W1, b1, x1);
  gcnL_kernel<<<NN / 4, 256, 0, stream>>>(adj, x1, W2, b2, x2);
  ab_kernel<<<NN, 128, 0, stream>>>(x2, We1, be1, Ab, Bb);
  pair_kernel<<<dim3(NN / 64, NN / 8), 512, 0, stream>>>(Ab, Bb, We2, be2, We3, be3, out);
}

// Round 3
// 863.701 us; speedup vs baseline: 1.9157x; 1.0268x over previous
//
#include <hip/hip_runtime.h>
#include <math.h>

#define NN 2048
#define HH 64

// ---------- layer 0: x0 = relu((adj @ nf) @ W0 + b0), nf is (N,4) ----------
__global__ __launch_bounds__(256) void gcn0_kernel(const float* __restrict__ adj,
                                                   const float* __restrict__ nf,
                                                   const float* __restrict__ W0,
                                                   const float* __restrict__ b0,
                                                   float* __restrict__ xout) {
  int w = threadIdx.x >> 6;        // wave 0..3 -> row
  int l = threadIdx.x & 63;        // lane
  int i = blockIdx.x * 4 + w;
  const float* arow = adj + (size_t)i * NN;
  double s0 = 0, s1 = 0, s2 = 0, s3 = 0;
  for (int k = l; k < NN; k += 64) {
    float a = arow[k];
    float4 v = *(const float4*)(nf + (size_t)k * 4);
    s0 += (double)a * (double)v.x;
    s1 += (double)a * (double)v.y;
    s2 += (double)a * (double)v.z;
    s3 += (double)a * (double)v.w;
  }
  #pragma unroll
  for (int m = 32; m >= 1; m >>= 1) {
    s0 += __shfl_xor(s0, m, 64);
    s1 += __shfl_xor(s1, m, 64);
    s2 += __shfl_xor(s2, m, 64);
    s3 += __shfl_xor(s3, m, 64);
  }
  double y = (double)b0[l];
  y += s0 * (double)W0[0 * HH + l];
  y += s1 * (double)W0[1 * HH + l];
  y += s2 * (double)W0[2 * HH + l];
  y += s3 * (double)W0[3 * HH + l];
  float r = (float)y;
  xout[(size_t)i * HH + l] = r > 0.f ? r : 0.f;
}

// ---------- layers 1,2: xout = relu((adj @ xin) @ W + b), xin is (N,64) ----------
#define KT 128
__global__ __launch_bounds__(256) void gcnL_kernel(const float* __restrict__ adj,
                                                   const float* __restrict__ xin,
                                                   const float* __restrict__ W,
                                                   const float* __restrict__ b,
                                                   float* __restrict__ xout) {
  __shared__ float xs[KT][HH];       // 32 KB
  __shared__ float adjs[4][KT];      // 2 KB
  __shared__ double sred[4][HH];     // 2 KB
  int tid = threadIdx.x;
  int w = tid >> 6, l = tid & 63;    // wave -> row, lane -> column
  int i0 = blockIdx.x * 4;
  double acc = 0.0;
  for (int k0 = 0; k0 < NN; k0 += KT) {
    __syncthreads();
    const float4* xsrc = (const float4*)(xin + (size_t)k0 * HH);
    float4* xdst = (float4*)&xs[0][0];
    for (int idx = tid; idx < KT * HH / 4; idx += 256) xdst[idx] = xsrc[idx];
    for (int idx = tid; idx < 4 * KT / 4; idx += 256) {
      int r = idx >> 5, c4 = idx & 31;
      *(float4*)&adjs[r][c4 * 4] =
          *(const float4*)(adj + (size_t)(i0 + r) * NN + k0 + c4 * 4);
    }
    __syncthreads();
    #pragma unroll 8
    for (int kk = 0; kk < KT; ++kk) {
      acc += (double)adjs[w][kk] * (double)xs[kk][l];
    }
  }
  sred[w][l] = acc;
  __syncthreads();
  double y = (double)b[l];
  #pragma unroll 8
  for (int d = 0; d < HH; ++d) y += sred[w][d] * (double)W[d * HH + l];
  float r = (float)y;
  xout[(size_t)(i0 + w) * HH + l] = r > 0.f ? r : 0.f;
}

// ---------- A = x2 @ We1[0:64,:] + be1 ; B = x2 @ We1[64:128,:] ----------
__global__ __launch_bounds__(128) void ab_kernel(const float* __restrict__ x2,
                                                 const float* __restrict__ We1,
                                                 const float* __restrict__ be1,
                                                 float* __restrict__ A,
                                                 float* __restrict__ B) {
  int i = blockIdx.x;
  int c = threadIdx.x;               // 0..127
  __shared__ float xrow[HH];
  if (threadIdx.x < HH) xrow[threadIdx.x] = x2[(size_t)i * HH + threadIdx.x];
  __syncthreads();
  float accA = be1[c], accB = 0.f;
  #pragma unroll 8
  for (int d = 0; d < HH; ++d) {
    float xv = xrow[d];
    accA = fmaf(xv, We1[d * 128 + c], accA);
    accB = fmaf(xv, We1[(HH + d) * 128 + c], accB);
  }
  A[(size_t)i * 128 + c] = accA;
  B[(size_t)i * 128 + c] = accB;
}

// ---------- pair MLP: register-blocked fp32 GEMM, fused h1 = relu(A_i + B_j) ----------
// Block: 8 i-rows x 64 j-cols x 64 c2. 512 threads; thread (c = tid&7, r = tid>>3)
// owns pair rows (i = i0 + (r>>3)), j = j0 + (r&7)*8 .. +7, and c2 = c*8 .. +7.
// Wave = one i-row. acc[8][8] must stay in arch VGPRs: loop temps kept under
// ~116 live so the allocator doesn't fission/AGPR-bounce (round-2 pathology).
__global__ __launch_bounds__(512, 4) void pair_kernel(const float* __restrict__ A,
                                                      const float* __restrict__ B,
                                                      const float* __restrict__ We2,
                                                      const float* __restrict__ be2,
                                                      const float* __restrict__ We3,
                                                      const float* __restrict__ be3,
                                                      float* __restrict__ out) {
  int j0 = blockIdx.x * 64;
  int i0 = blockIdx.y * 8;
  if (j0 + 63 <= i0) return;         // tile entirely below/on diagonal
  __shared__ float We2s[128 * 64];   // 32 KB  [k][c2]
  __shared__ float Bt[128 * 64];     // 32 KB  [k][j] transposed, stride 64
  __shared__ float As[8 * 128];      // 4 KB   [i][k]
  __shared__ float be2s[64];
  __shared__ float We3s[64];
  int tid = threadIdx.x;
  {
    const float4* s = (const float4*)We2;
    float4* d = (float4*)We2s;
    #pragma unroll
    for (int it = 0; it < 4; ++it) d[tid + it * 512] = s[tid + it * 512];
  }
  if (tid < 256) {
    int ir = tid >> 5, kc = tid & 31;
    *(float4*)&As[ir * 128 + kc * 4] =
        *(const float4*)(A + (size_t)(i0 + ir) * 128 + kc * 4);
  }
  // Bt staging: lane j fast -> LDS write addr = (q*4+z)*64 + j, j spans 64
  // consecutive lanes => 2-way bank access (free). Global read is 16B per lane
  // at stride 512B (uncoalesced but tiny + L2-resident).
  {
    int j = tid & 63;
    int qb = tid >> 6;               // 0..7
    #pragma unroll
    for (int it = 0; it < 4; ++it) {
      int q = qb + it * 8;           // 0..31 k-quad
      float4 gb = *(const float4*)(B + (size_t)(j0 + j) * 128 + q * 4);
      Bt[(q * 4 + 0) * 64 + j] = gb.x;
      Bt[(q * 4 + 1) * 64 + j] = gb.y;
      Bt[(q * 4 + 2) * 64 + j] = gb.z;
      Bt[(q * 4 + 3) * 64 + j] = gb.w;
    }
  }
  if (tid < 64) { be2s[tid] = be2[tid]; We3s[tid] = We3[tid]; }
  __syncthreads();

  int c = tid & 7;                   // c2 chunk
  int r = tid >> 3;                  // 0..63
  int ir = r >> 3;                   // i within tile (wave-uniform)
  int jc = r & 7;                    // j chunk
  int i = i0 + ir;
  int jb = j0 + jc * 8;
  int c8 = c * 8;
  int jc8 = jc * 8;

  float acc[8][8];
  #pragma unroll
  for (int m = 0; m < 8; ++m) {
    #pragma unroll
    for (int n = 0; n < 8; ++n) acc[m][n] = be2s[c8 + n];
  }

  const float* Arow = &As[ir * 128];
  #pragma unroll 2
  for (int kk = 0; kk < 128; ++kk) {
    float a = Arow[kk];              // wave-uniform broadcast
    float4 bA = *(const float4*)&Bt[kk * 64 + jc8];
    float4 bB = *(const float4*)&Bt[kk * 64 + jc8 + 4];
    float h0 = fmaxf(a + bA.x, 0.f);
    float h1 = fmaxf(a + bA.y, 0.f);
    float h2 = fmaxf(a + bA.z, 0.f);
    float h3 = fmaxf(a + bA.w, 0.f);
    float h4 = fmaxf(a + bB.x, 0.f);
    float h5 = fmaxf(a + bB.y, 0.f);
    float h6 = fmaxf(a + bB.z, 0.f);
    float h7 = fmaxf(a + bB.w, 0.f);
    {
      float4 wA = *(const float4*)&We2s[kk * 64 + c8];
#define PK_A(m, hm)                                     \
      acc[m][0] = fmaf(hm, wA.x, acc[m][0]);            \
      acc[m][1] = fmaf(hm, wA.y, acc[m][1]);            \
      acc[m][2] = fmaf(hm, wA.z, acc[m][2]);            \
      acc[m][3] = fmaf(hm, wA.w, acc[m][3]);
      PK_A(0, h0) PK_A(1, h1) PK_A(2, h2) PK_A(3, h3)
      PK_A(4, h4) PK_A(5, h5) PK_A(6, h6) PK_A(7, h7)
#undef PK_A
    }
    {
      float4 wB = *(const float4*)&We2s[kk * 64 + c8 + 4];
#define PK_B(m, hm)                                     \
      acc[m][4] = fmaf(hm, wB.x, acc[m][4]);            \
      acc[m][5] = fmaf(hm, wB.y, acc[m][5]);            \
      acc[m][6] = fmaf(hm, wB.z, acc[m][6]);            \
      acc[m][7] = fmaf(hm, wB.w, acc[m][7]);
      PK_B(0, h0) PK_B(1, h1) PK_B(2, h2) PK_B(3, h3)
      PK_B(4, h4) PK_B(5, h5) PK_B(6, h6) PK_B(7, h7)
#undef PK_B
    }
  }

  // epilogue: h2 = relu(acc); partial dot with We3 over this thread's 8 c2
  float part[8];
  #pragma unroll
  for (int m = 0; m < 8; ++m) {
    float s = 0.f;
    #pragma unroll
    for (int n = 0; n < 8; ++n)
      s = fmaf(fmaxf(acc[m][n], 0.f), We3s[c8 + n], s);
    part[m] = s;
  }
  // reduce across the 8 c-threads (lanes differing in bits 0..2)
  #pragma unroll
  for (int m = 0; m < 8; ++m) {
    part[m] += __shfl_xor(part[m], 1, 64);
    part[m] += __shfl_xor(part[m], 2, 64);
    part[m] += __shfl_xor(part[m], 4, 64);
  }
  if (c == 0) {
    float bias = be3[0];
    #pragma unroll
    for (int m = 0; m < 8; ++m) {
      int j = jb + m;
      if (j > i) {
        float logit = part[m] + bias;
        float prob = 1.0f / (1.0f + expf(-logit));
        int idx = i * (NN - 1) - (i * (i - 1)) / 2 + (j - i - 1);
        out[idx] = prob;
      }
    }
  }
}

extern "C" void kernel_launch(void* const* d_in, const int* in_sizes, int n_in,
                              void* d_out, int out_size, void* d_ws, size_t ws_size,
                              hipStream_t stream) {
  (void)in_sizes; (void)n_in; (void)out_size; (void)ws_size;
  const float* nf  = (const float*)d_in[0];
  const float* adj = (const float*)d_in[1];
  const float* W0  = (const float*)d_in[2];
  const float* b0  = (const float*)d_in[3];
  const float* W1  = (const float*)d_in[4];
  const float* b1  = (const float*)d_in[5];
  const float* W2  = (const float*)d_in[6];
  const float* b2  = (const float*)d_in[7];
  const float* We1 = (const float*)d_in[8];
  const float* be1 = (const float*)d_in[9];
  const float* We2 = (const float*)d_in[10];
  const float* be2 = (const float*)d_in[11];
  const float* We3 = (const float*)d_in[12];
  const float* be3 = (const float*)d_in[13];
  float* out = (float*)d_out;

  char* ws = (char*)d_ws;
  float* x0 = (float*)(ws);                       // 512 KB
  float* x1 = (float*)(ws + (512 << 10));         // 512 KB
  float* x2 = (float*)(ws + (1024 << 10));        // 512 KB
  float* Ab = (float*)(ws + (1536 << 10));        // 1 MB
  float* Bb = (float*)(ws + (2560 << 10));        // 1 MB

  gcn0_kernel<<<NN / 4, 256, 0, stream>>>(adj, nf, W0, b0, x0);
  gcnL_kernel<<<NN / 4, 256, 0, stream>>>(adj, x0, W1, b1, x1);
  gcnL_kernel<<<NN / 4, 256, 0, stream>>>(adj, x1, W2, b2, x2);
  ab_kernel<<<NN, 128, 0, stream>>>(x2, We1, be1, Ab, Bb);
  pair_kernel<<<dim3(NN / 64, NN / 8), 512, 0, stream>>>(Ab, Bb, We2, be2, We3, be3, out);
}

// Round 4
// 375.636 us; speedup vs baseline: 4.4047x; 2.2993x over previous
//
#include <hip/hip_runtime.h>
#include <math.h>

#define NN 2048
#define HH 64

typedef _Float16 half8 __attribute__((ext_vector_type(8)));
typedef float f32x4 __attribute__((ext_vector_type(4)));

#define SH (1.0f / 256.0f)
#define INV_SH 256.0f
#define BPAD 132  // f32 row stride (528 B): bank = 4*row mod 32 -> 2-way (free)
#define WPAD 136  // f16 row stride (272 B): bank = 4*row mod 32 -> 2-way (free)

// ---------- layer 0: x0 = relu((adj @ nf) @ W0 + b0), nf is (N,4) ----------
__global__ __launch_bounds__(256) void gcn0_kernel(const float* __restrict__ adj,
                                                   const float* __restrict__ nf,
                                                   const float* __restrict__ W0,
                                                   const float* __restrict__ b0,
                                                   float* __restrict__ xout) {
  int w = threadIdx.x >> 6;
  int l = threadIdx.x & 63;
  int i = blockIdx.x * 4 + w;
  const float* arow = adj + (size_t)i * NN;
  double s0 = 0, s1 = 0, s2 = 0, s3 = 0;
  for (int k = l; k < NN; k += 64) {
    float a = arow[k];
    float4 v = *(const float4*)(nf + (size_t)k * 4);
    s0 += (double)a * (double)v.x;
    s1 += (double)a * (double)v.y;
    s2 += (double)a * (double)v.z;
    s3 += (double)a * (double)v.w;
  }
  #pragma unroll
  for (int m = 32; m >= 1; m >>= 1) {
    s0 += __shfl_xor(s0, m, 64);
    s1 += __shfl_xor(s1, m, 64);
    s2 += __shfl_xor(s2, m, 64);
    s3 += __shfl_xor(s3, m, 64);
  }
  double y = (double)b0[l];
  y += s0 * (double)W0[0 * HH + l];
  y += s1 * (double)W0[1 * HH + l];
  y += s2 * (double)W0[2 * HH + l];
  y += s3 * (double)W0[3 * HH + l];
  float r = (float)y;
  xout[(size_t)i * HH + l] = r > 0.f ? r : 0.f;
}

// ---------- layers 1,2: xout = relu((adj @ xin) @ W + b), xin is (N,64) ----------
#define KT 128
__global__ __launch_bounds__(256) void gcnL_kernel(const float* __restrict__ adj,
                                                   const float* __restrict__ xin,
                                                   const float* __restrict__ W,
                                                   const float* __restrict__ b,
                                                   float* __restrict__ xout) {
  __shared__ float xs[KT][HH];
  __shared__ float adjs[4][KT];
  __shared__ double sred[4][HH];
  int tid = threadIdx.x;
  int w = tid >> 6, l = tid & 63;
  int i0 = blockIdx.x * 4;
  double acc = 0.0;
  for (int k0 = 0; k0 < NN; k0 += KT) {
    __syncthreads();
    const float4* xsrc = (const float4*)(xin + (size_t)k0 * HH);
    float4* xdst = (float4*)&xs[0][0];
    for (int idx = tid; idx < KT * HH / 4; idx += 256) xdst[idx] = xsrc[idx];
    for (int idx = tid; idx < 4 * KT / 4; idx += 256) {
      int r = idx >> 5, c4 = idx & 31;
      *(float4*)&adjs[r][c4 * 4] =
          *(const float4*)(adj + (size_t)(i0 + r) * NN + k0 + c4 * 4);
    }
    __syncthreads();
    #pragma unroll 8
    for (int kk = 0; kk < KT; ++kk) {
      acc += (double)adjs[w][kk] * (double)xs[kk][l];
    }
  }
  sred[w][l] = acc;
  __syncthreads();
  double y = (double)b[l];
  #pragma unroll 8
  for (int d = 0; d < HH; ++d) y += sred[w][d] * (double)W[d * HH + l];
  float r = (float)y;
  xout[(size_t)(i0 + w) * HH + l] = r > 0.f ? r : 0.f;
}

// ---------- A = x2 @ We1[0:64,:] + be1 ; B = x2 @ We1[64:128,:] ----------
__global__ __launch_bounds__(128) void ab_kernel(const float* __restrict__ x2,
                                                 const float* __restrict__ We1,
                                                 const float* __restrict__ be1,
                                                 float* __restrict__ A,
                                                 float* __restrict__ B) {
  int i = blockIdx.x;
  int c = threadIdx.x;
  __shared__ float xrow[HH];
  if (threadIdx.x < HH) xrow[threadIdx.x] = x2[(size_t)i * HH + threadIdx.x];
  __syncthreads();
  float accA = be1[c], accB = 0.f;
  #pragma unroll 8
  for (int d = 0; d < HH; ++d) {
    float xv = xrow[d];
    accA = fmaf(xv, We1[d * 128 + c], accA);
    accB = fmaf(xv, We1[(HH + d) * 128 + c], accB);
  }
  A[(size_t)i * 128 + c] = accA;
  B[(size_t)i * 128 + c] = accB;
}

// ---------- pair MLP via MFMA (split-f16): tile = 16 i x 64 j, 4 waves ----------
// Wave handles 1 i x 64 j per superchunk (4 superchunks). MFMA 16x16x32_f16:
// M = 16 pairs (j-subtile), N = 16 c2 (4 n-tiles), K = 128 (4 k-steps).
// A-frag: lane holds H[l&15][8*(l>>4)+q]; B-frag: lane holds W[8*(l>>4)+q][l&15]
// via transposed LDS copy. C/D: col = l&15, row = 4*(l>>4)+reg [m89-verified].
// Precision: H,W split hi/lo f16; acc = Hh@Wh + Hh@Wl + Hl@Wh (drop lo*lo ~2^-22).
// H scaled by 2^-8 at A/B staging (relu commutes, be2 seeded scaled, epilogue *256).
__global__ __launch_bounds__(256, 2) void pair_kernel(const float* __restrict__ A,
                                                      const float* __restrict__ B,
                                                      const float* __restrict__ We2,
                                                      const float* __restrict__ be2,
                                                      const float* __restrict__ We3,
                                                      const float* __restrict__ be3,
                                                      float* __restrict__ out) {
  int j0 = blockIdx.x * 64;
  int i0 = blockIdx.y * 16;
  if (i0 >= j0 + 63) return;         // no pair (i<j) in tile
  __shared__ float As[16][BPAD];     // 8.4 KB (scaled A rows)
  __shared__ float Bs[64][BPAD];     // 33.8 KB (scaled B rows)
  __shared__ _Float16 Wh[64][WPAD];  // 17.4 KB  We2^T hi  [c2][k]
  __shared__ _Float16 Wl[64][WPAD];  // 17.4 KB  We2^T lo  [c2][k]
  __shared__ float be2s[64];
  __shared__ float We3s[64];
  int tid = threadIdx.x;
  #pragma unroll
  for (int t = 0; t < 2; ++t) {
    int idx = tid + t * 256;         // 0..511
    int r = idx >> 5, c4 = idx & 31;
    float4 v = *(const float4*)(A + (size_t)(i0 + r) * 128 + c4 * 4);
    float* d = &As[r][c4 * 4];
    d[0] = v.x * SH; d[1] = v.y * SH; d[2] = v.z * SH; d[3] = v.w * SH;
  }
  #pragma unroll
  for (int t = 0; t < 8; ++t) {
    int idx = tid + t * 256;         // 0..2047
    int r = idx >> 5, c4 = idx & 31;
    float4 v = *(const float4*)(B + (size_t)(j0 + r) * 128 + c4 * 4);
    float* d = &Bs[r][c4 * 4];
    d[0] = v.x * SH; d[1] = v.y * SH; d[2] = v.z * SH; d[3] = v.w * SH;
  }
  #pragma unroll
  for (int t = 0; t < 32; ++t) {
    int idx = tid + t * 256;         // 0..8191, coalesced read of We2[k][c2]
    int k = idx >> 6, c2 = idx & 63;
    float wv = We2[idx];
    _Float16 hi = (_Float16)wv;
    float lo = wv - (float)hi;
    Wh[c2][k] = hi;
    Wl[c2][k] = (_Float16)lo;
  }
  if (tid < 64) { be2s[tid] = be2[tid]; We3s[tid] = We3[tid]; }
  __syncthreads();

  int w = tid >> 6, l = tid & 63;
  int r = l & 15, g = l >> 4;
  float be3v = be3[0];
  float w3[4], sb[4];
  #pragma unroll
  for (int nt = 0; nt < 4; ++nt) {
    w3[nt] = We3s[nt * 16 + r];
    sb[nt] = SH * be2s[nt * 16 + r];
  }

  for (int iw = 0; iw < 4; ++iw) {
    int ir = w * 4 + iw;
    int i = i0 + ir;
    if (i >= j0 + 63) continue;      // no j in this tile exceeds i
    f32x4 acc[4][4];
    #pragma unroll
    for (int js = 0; js < 4; ++js) {
      #pragma unroll
      for (int nt = 0; nt < 4; ++nt) {
        acc[js][nt][0] = sb[nt]; acc[js][nt][1] = sb[nt];
        acc[js][nt][2] = sb[nt]; acc[js][nt][3] = sb[nt];
      }
    }
    #pragma unroll
    for (int ks = 0; ks < 4; ++ks) {
      int kb = ks * 32 + 8 * g;
      half8 wh[4], wl[4];
      #pragma unroll
      for (int nt = 0; nt < 4; ++nt) {
        wh[nt] = *(const half8*)&Wh[nt * 16 + r][kb];
        wl[nt] = *(const half8*)&Wl[nt * 16 + r][kb];
      }
      float4 a0 = *(const float4*)&As[ir][kb];
      float4 a1 = *(const float4*)&As[ir][kb + 4];
      #pragma unroll
      for (int js = 0; js < 4; ++js) {
        float4 b0 = *(const float4*)&Bs[js * 16 + r][kb];
        float4 b1 = *(const float4*)&Bs[js * 16 + r][kb + 4];
        float xs_[8];
        xs_[0] = fmaxf(a0.x + b0.x, 0.f);
        xs_[1] = fmaxf(a0.y + b0.y, 0.f);
        xs_[2] = fmaxf(a0.z + b0.z, 0.f);
        xs_[3] = fmaxf(a0.w + b0.w, 0.f);
        xs_[4] = fmaxf(a1.x + b1.x, 0.f);
        xs_[5] = fmaxf(a1.y + b1.y, 0.f);
        xs_[6] = fmaxf(a1.z + b1.z, 0.f);
        xs_[7] = fmaxf(a1.w + b1.w, 0.f);
        half8 hh, hl;
        #pragma unroll
        for (int q = 0; q < 8; ++q) {
          _Float16 hi = (_Float16)xs_[q];
          hh[q] = hi;
          hl[q] = (_Float16)(xs_[q] - (float)hi);
        }
        #pragma unroll
        for (int nt = 0; nt < 4; ++nt) {
          acc[js][nt] = __builtin_amdgcn_mfma_f32_16x16x32_f16(hh, wh[nt], acc[js][nt], 0, 0, 0);
          acc[js][nt] = __builtin_amdgcn_mfma_f32_16x16x32_f16(hh, wl[nt], acc[js][nt], 0, 0, 0);
          acc[js][nt] = __builtin_amdgcn_mfma_f32_16x16x32_f16(hl, wh[nt], acc[js][nt], 0, 0, 0);
        }
      }
    }
    // epilogue: h2 = relu(acc)/SH; logit = sum h2*We3 + be3
    #pragma unroll
    for (int js = 0; js < 4; ++js) {
      float p0 = 0.f, p1 = 0.f, p2 = 0.f, p3 = 0.f;
      #pragma unroll
      for (int nt = 0; nt < 4; ++nt) {
        f32x4 v = acc[js][nt];
        p0 += fmaxf(v[0], 0.f) * w3[nt];
        p1 += fmaxf(v[1], 0.f) * w3[nt];
        p2 += fmaxf(v[2], 0.f) * w3[nt];
        p3 += fmaxf(v[3], 0.f) * w3[nt];
      }
      #pragma unroll
      for (int m = 1; m <= 8; m <<= 1) {
        p0 += __shfl_xor(p0, m, 64);
        p1 += __shfl_xor(p1, m, 64);
        p2 += __shfl_xor(p2, m, 64);
        p3 += __shfl_xor(p3, m, 64);
      }
      if (r == 0) {
        int jb2 = j0 + js * 16 + 4 * g;
        int j;
        float logit, prob;
        j = jb2 + 0;
        if (j > i) {
          logit = p0 * INV_SH + be3v;
          prob = 1.0f / (1.0f + expf(-logit));
          out[i * (NN - 1) - (i * (i - 1)) / 2 + (j - i - 1)] = prob;
        }
        j = jb2 + 1;
        if (j > i) {
          logit = p1 * INV_SH + be3v;
          prob = 1.0f / (1.0f + expf(-logit));
          out[i * (NN - 1) - (i * (i - 1)) / 2 + (j - i - 1)] = prob;
        }
        j = jb2 + 2;
        if (j > i) {
          logit = p2 * INV_SH + be3v;
          prob = 1.0f / (1.0f + expf(-logit));
          out[i * (NN - 1) - (i * (i - 1)) / 2 + (j - i - 1)] = prob;
        }
        j = jb2 + 3;
        if (j > i) {
          logit = p3 * INV_SH + be3v;
          prob = 1.0f / (1.0f + expf(-logit));
          out[i * (NN - 1) - (i * (i - 1)) / 2 + (j - i - 1)] = prob;
        }
      }
    }
  }
}

extern "C" void kernel_launch(void* const* d_in, const int* in_sizes, int n_in,
                              void* d_out, int out_size, void* d_ws, size_t ws_size,
                              hipStream_t stream) {
  (void)in_sizes; (void)n_in; (void)out_size; (void)ws_size;
  const float* nf  = (const float*)d_in[0];
  const float* adj = (const float*)d_in[1];
  const float* W0  = (const float*)d_in[2];
  const float* b0  = (const float*)d_in[3];
  const float* W1  = (const float*)d_in[4];
  const float* b1  = (const float*)d_in[5];
  const float* W2  = (const float*)d_in[6];
  const float* b2  = (const float*)d_in[7];
  const float* We1 = (const float*)d_in[8];
  const float* be1 = (const float*)d_in[9];
  const float* We2 = (const float*)d_in[10];
  const float* be2 = (const float*)d_in[11];
  const float* We3 = (const float*)d_in[12];
  const float* be3 = (const float*)d_in[13];
  float* out = (float*)d_out;

  char* ws = (char*)d_ws;
  float* x0 = (float*)(ws);                       // 512 KB
  float* x1 = (float*)(ws + (512 << 10));         // 512 KB
  float* x2 = (float*)(ws + (1024 << 10));        // 512 KB
  float* Ab = (float*)(ws + (1536 << 10));        // 1 MB
  float* Bb = (float*)(ws + (2560 << 10));        // 1 MB

  gcn0_kernel<<<NN / 4, 256, 0, stream>>>(adj, nf, W0, b0, x0);
  gcnL_kernel<<<NN / 4, 256, 0, stream>>>(adj, x0, W1, b1, x1);
  gcnL_kernel<<<NN / 4, 256, 0, stream>>>(adj, x1, W2, b2, x2);
  ab_kernel<<<NN, 128, 0, stream>>>(x2, We1, be1, Ab, Bb);
  pair_kernel<<<dim3(NN / 64, NN / 16), 256, 0, stream>>>(Ab, Bb, We2, be2, We3, be3, out);
}

// Round 6
// 362.488 us; speedup vs baseline: 4.5645x; 1.0363x over previous
//
#include <hip/hip_runtime.h>
#include <math.h>

#define NN 2048
#define HH 64

typedef _Float16 half8 __attribute__((ext_vector_type(8)));
typedef _Float16 half2_t __attribute__((ext_vector_type(2)));
typedef float f32x4 __attribute__((ext_vector_type(4)));

#define SH (1.0f / 256.0f)
#define INV_SH 256.0f
#define BPAD 132  // f32 row stride: 2-way bank phases (free)
#define WPAD 136  // f16 row stride (272 B = 68 dwords): 2-way phases (free)

#if defined(__has_builtin)
#if __has_builtin(__builtin_amdgcn_cvt_pkrtz)
#define PKRTZ(a, b) ((half2_t)__builtin_amdgcn_cvt_pkrtz((a), (b)))
#endif
#endif
#ifndef PKRTZ
#define PKRTZ(a, b) ((half2_t){(_Float16)(a), (_Float16)(b)})
#endif

union H8u { half2_t h2[4]; half8 h8; };

// ---------- layer 0: x0 = relu((adj @ nf) @ W0 + b0), nf is (N,4) ----------
__global__ __launch_bounds__(256) void gcn0_kernel(const float* __restrict__ adj,
                                                   const float* __restrict__ nf,
                                                   const float* __restrict__ W0,
                                                   const float* __restrict__ b0,
                                                   float* __restrict__ xout) {
  int w = threadIdx.x >> 6;
  int l = threadIdx.x & 63;
  int i = blockIdx.x * 4 + w;
  const float* arow = adj + (size_t)i * NN;
  double s0 = 0, s1 = 0, s2 = 0, s3 = 0;
  for (int k = l; k < NN; k += 64) {
    float a = arow[k];
    float4 v = *(const float4*)(nf + (size_t)k * 4);
    s0 += (double)a * (double)v.x;
    s1 += (double)a * (double)v.y;
    s2 += (double)a * (double)v.z;
    s3 += (double)a * (double)v.w;
  }
  #pragma unroll
  for (int m = 32; m >= 1; m >>= 1) {
    s0 += __shfl_xor(s0, m, 64);
    s1 += __shfl_xor(s1, m, 64);
    s2 += __shfl_xor(s2, m, 64);
    s3 += __shfl_xor(s3, m, 64);
  }
  double y = (double)b0[l];
  y += s0 * (double)W0[0 * HH + l];
  y += s1 * (double)W0[1 * HH + l];
  y += s2 * (double)W0[2 * HH + l];
  y += s3 * (double)W0[3 * HH + l];
  float r = (float)y;
  xout[(size_t)i * HH + l] = r > 0.f ? r : 0.f;
}

// ---------- layers 1,2: xout = relu((adj @ xin) @ W + b); layer2 fuses A/B ----------
#define KT 128
__global__ __launch_bounds__(256) void gcnL_kernel(const float* __restrict__ adj,
                                                   const float* __restrict__ xin,
                                                   const float* __restrict__ W,
                                                   const float* __restrict__ b,
                                                   float* __restrict__ xout,
                                                   const float* __restrict__ We1,
                                                   const float* __restrict__ be1,
                                                   float* __restrict__ Aout,
                                                   float* __restrict__ Bout) {
  __shared__ float xs[KT][HH];
  __shared__ float adjs[4][KT];
  __shared__ double sred[4][HH];
  __shared__ float xr2[4][HH];
  int tid = threadIdx.x;
  int w = tid >> 6, l = tid & 63;
  int i0 = blockIdx.x * 4;
  double acc = 0.0;
  for (int k0 = 0; k0 < NN; k0 += KT) {
    __syncthreads();
    const float4* xsrc = (const float4*)(xin + (size_t)k0 * HH);
    float4* xdst = (float4*)&xs[0][0];
    for (int idx = tid; idx < KT * HH / 4; idx += 256) xdst[idx] = xsrc[idx];
    for (int idx = tid; idx < 4 * KT / 4; idx += 256) {
      int r = idx >> 5, c4 = idx & 31;
      *(float4*)&adjs[r][c4 * 4] =
          *(const float4*)(adj + (size_t)(i0 + r) * NN + k0 + c4 * 4);
    }
    __syncthreads();
    #pragma unroll 8
    for (int kk = 0; kk < KT; ++kk) {
      acc += (double)adjs[w][kk] * (double)xs[kk][l];
    }
  }
  sred[w][l] = acc;
  __syncthreads();
  double y = (double)b[l];
  #pragma unroll 8
  for (int d = 0; d < HH; ++d) y += sred[w][d] * (double)W[d * HH + l];
  float r = (float)y;
  float rres = r > 0.f ? r : 0.f;
  xout[(size_t)(i0 + w) * HH + l] = rres;
  if (Aout != nullptr) {
    // fused edge-MLP layer-1 projection: A = (x2@We1_top + be1)*SH, B = x2@We1_bot*SH
    xr2[w][l] = rres;
    __syncthreads();
    #pragma unroll
    for (int t = 0; t < 2; ++t) {
      int idx = tid + t * 256;         // 0..511
      int rr = idx >> 7, c = idx & 127;
      const float* xr = xr2[rr];
      float accA = be1[c], accB = 0.f;
      #pragma unroll 8
      for (int d = 0; d < HH; ++d) {
        float xv = xr[d];
        accA = fmaf(xv, We1[d * 128 + c], accA);
        accB = fmaf(xv, We1[(HH + d) * 128 + c], accB);
      }
      Aout[(size_t)(i0 + rr) * 128 + c] = accA * SH;
      Bout[(size_t)(i0 + rr) * 128 + c] = accB * SH;
    }
  }
}

// ---------- one-shot We2 split: Wh/Wl f16 [c2][k] row-major ----------
__global__ __launch_bounds__(256) void wsplit_kernel(const float* __restrict__ We2,
                                                     _Float16* __restrict__ Whg,
                                                     _Float16* __restrict__ Wlg) {
  int idx = blockIdx.x * 256 + threadIdx.x;   // 0..8191
  int k = idx >> 6, c2 = idx & 63;
  float wv = We2[idx];
  _Float16 hi = (_Float16)wv;
  float lo = wv - (float)hi;
  Whg[c2 * 128 + k] = hi;
  Wlg[c2 * 128 + k] = (_Float16)lo;
}

// ---------- pair MLP via MFMA (split-f16), 16i x 64j tile, 4 waves ----------
// Wave handles i rows w*4..w*4+3 as two 2-i iterations; per (ks,js): B/W frags
// shared by both i-streams -> 24 MFMAs per 2 h-forms. All staging = b128 copies.
__global__ __launch_bounds__(256, 2) void pair_kernel(const float* __restrict__ A,
                                                      const float* __restrict__ B,
                                                      const _Float16* __restrict__ Whg,
                                                      const _Float16* __restrict__ Wlg,
                                                      const float* __restrict__ be2,
                                                      const float* __restrict__ We3,
                                                      const float* __restrict__ be3,
                                                      float* __restrict__ out) {
  int j0 = blockIdx.x * 64;
  int i0 = blockIdx.y * 16;
  if (i0 >= j0 + 63) return;         // no pair (i<j) in tile
  __shared__ float As[16][BPAD];     // 8.4 KB (pre-scaled)
  __shared__ float Bs[64][BPAD];     // 33.8 KB (pre-scaled)
  __shared__ _Float16 Wh[64][WPAD];  // 17.4 KB [c2][k]
  __shared__ _Float16 Wl[64][WPAD];  // 17.4 KB
  __shared__ float be2s[64];
  __shared__ float We3s[64];
  int tid = threadIdx.x;
  #pragma unroll
  for (int t = 0; t < 2; ++t) {
    int idx = tid + t * 256;         // 0..511
    int r = idx >> 5, c4 = idx & 31;
    *(float4*)&As[r][c4 * 4] = *(const float4*)(A + (size_t)(i0 + r) * 128 + c4 * 4);
  }
  #pragma unroll
  for (int t = 0; t < 8; ++t) {
    int idx = tid + t * 256;         // 0..2047
    int r = idx >> 5, c4 = idx & 31;
    *(float4*)&Bs[r][c4 * 4] = *(const float4*)(B + (size_t)(j0 + r) * 128 + c4 * 4);
  }
  // W staging: 64 rows x 16 chunks (8 f16 each) per array => 1024 chunks => t<4
  #pragma unroll
  for (int t = 0; t < 4; ++t) {
    int idx = tid + t * 256;         // 0..1023
    int r = idx >> 4, ch = idx & 15;
    *(half8*)&Wh[r][ch * 8] = *(const half8*)(Whg + r * 128 + ch * 8);
    *(half8*)&Wl[r][ch * 8] = *(const half8*)(Wlg + r * 128 + ch * 8);
  }
  if (tid < 64) { be2s[tid] = be2[tid]; We3s[tid] = We3[tid]; }
  __syncthreads();

  int w = tid >> 6, l = tid & 63;
  int r = l & 15, g = l >> 4;
  float be3v = be3[0];
  float w3[4], sb[4];
  #pragma unroll
  for (int nt = 0; nt < 4; ++nt) {
    w3[nt] = We3s[nt * 16 + r];
    sb[nt] = SH * be2s[nt * 16 + r];
  }

  #pragma unroll
  for (int ip = 0; ip < 2; ++ip) {
    int irA = w * 4 + ip * 2;
    int irB = irA + 1;
    int iA = i0 + irA, iB = i0 + irB;
    f32x4 accA[4][4], accB[4][4];
    #pragma unroll
    for (int js = 0; js < 4; ++js) {
      #pragma unroll
      for (int nt = 0; nt < 4; ++nt) {
        accA[js][nt][0] = sb[nt]; accA[js][nt][1] = sb[nt];
        accA[js][nt][2] = sb[nt]; accA[js][nt][3] = sb[nt];
        accB[js][nt][0] = sb[nt]; accB[js][nt][1] = sb[nt];
        accB[js][nt][2] = sb[nt]; accB[js][nt][3] = sb[nt];
      }
    }
    #pragma unroll
    for (int ks = 0; ks < 4; ++ks) {
      int kb = ks * 32 + 8 * g;
      half8 wh[4], wl[4];
      #pragma unroll
      for (int nt = 0; nt < 4; ++nt) {
        wh[nt] = *(const half8*)&Wh[nt * 16 + r][kb];
        wl[nt] = *(const half8*)&Wl[nt * 16 + r][kb];
      }
      float4 aA0 = *(const float4*)&As[irA][kb];
      float4 aA1 = *(const float4*)&As[irA][kb + 4];
      float4 aB0 = *(const float4*)&As[irB][kb];
      float4 aB1 = *(const float4*)&As[irB][kb + 4];
      #pragma unroll
      for (int js = 0; js < 4; ++js) {
        float4 b0 = *(const float4*)&Bs[js * 16 + r][kb];
        float4 b1 = *(const float4*)&Bs[js * 16 + r][kb + 4];
        // stream A
        float sA0 = fmaxf(aA0.x + b0.x, 0.f);
        float sA1 = fmaxf(aA0.y + b0.y, 0.f);
        float sA2 = fmaxf(aA0.z + b0.z, 0.f);
        float sA3 = fmaxf(aA0.w + b0.w, 0.f);
        float sA4 = fmaxf(aA1.x + b1.x, 0.f);
        float sA5 = fmaxf(aA1.y + b1.y, 0.f);
        float sA6 = fmaxf(aA1.z + b1.z, 0.f);
        float sA7 = fmaxf(aA1.w + b1.w, 0.f);
        H8u hhA, hlA;
        hhA.h2[0] = PKRTZ(sA0, sA1);
        hhA.h2[1] = PKRTZ(sA2, sA3);
        hhA.h2[2] = PKRTZ(sA4, sA5);
        hhA.h2[3] = PKRTZ(sA6, sA7);
        hlA.h2[0] = PKRTZ(sA0 - (float)hhA.h2[0][0], sA1 - (float)hhA.h2[0][1]);
        hlA.h2[1] = PKRTZ(sA2 - (float)hhA.h2[1][0], sA3 - (float)hhA.h2[1][1]);
        hlA.h2[2] = PKRTZ(sA4 - (float)hhA.h2[2][0], sA5 - (float)hhA.h2[2][1]);
        hlA.h2[3] = PKRTZ(sA6 - (float)hhA.h2[3][0], sA7 - (float)hhA.h2[3][1]);
        // stream B
        float sB0 = fmaxf(aB0.x + b0.x, 0.f);
        float sB1 = fmaxf(aB0.y + b0.y, 0.f);
        float sB2 = fmaxf(aB0.z + b0.z, 0.f);
        float sB3 = fmaxf(aB0.w + b0.w, 0.f);
        float sB4 = fmaxf(aB1.x + b1.x, 0.f);
        float sB5 = fmaxf(aB1.y + b1.y, 0.f);
        float sB6 = fmaxf(aB1.z + b1.z, 0.f);
        float sB7 = fmaxf(aB1.w + b1.w, 0.f);
        H8u hhB, hlB;
        hhB.h2[0] = PKRTZ(sB0, sB1);
        hhB.h2[1] = PKRTZ(sB2, sB3);
        hhB.h2[2] = PKRTZ(sB4, sB5);
        hhB.h2[3] = PKRTZ(sB6, sB7);
        hlB.h2[0] = PKRTZ(sB0 - (float)hhB.h2[0][0], sB1 - (float)hhB.h2[0][1]);
        hlB.h2[1] = PKRTZ(sB2 - (float)hhB.h2[1][0], sB3 - (float)hhB.h2[1][1]);
        hlB.h2[2] = PKRTZ(sB4 - (float)hhB.h2[2][0], sB5 - (float)hhB.h2[2][1]);
        hlB.h2[3] = PKRTZ(sB6 - (float)hhB.h2[3][0], sB7 - (float)hhB.h2[3][1]);
        #pragma unroll
        for (int nt = 0; nt < 4; ++nt) {
          accA[js][nt] = __builtin_amdgcn_mfma_f32_16x16x32_f16(hhA.h8, wh[nt], accA[js][nt], 0, 0, 0);
          accA[js][nt] = __builtin_amdgcn_mfma_f32_16x16x32_f16(hhA.h8, wl[nt], accA[js][nt], 0, 0, 0);
          accA[js][nt] = __builtin_amdgcn_mfma_f32_16x16x32_f16(hlA.h8, wh[nt], accA[js][nt], 0, 0, 0);
          accB[js][nt] = __builtin_amdgcn_mfma_f32_16x16x32_f16(hhB.h8, wh[nt], accB[js][nt], 0, 0, 0);
          accB[js][nt] = __builtin_amdgcn_mfma_f32_16x16x32_f16(hhB.h8, wl[nt], accB[js][nt], 0, 0, 0);
          accB[js][nt] = __builtin_amdgcn_mfma_f32_16x16x32_f16(hlB.h8, wh[nt], accB[js][nt], 0, 0, 0);
        }
      }
    }
    // epilogue for both i-streams
#define EPILOG(ACC, IVAR)                                                     \
    _Pragma("unroll")                                                         \
    for (int js = 0; js < 4; ++js) {                                          \
      float p0 = 0.f, p1 = 0.f, p2 = 0.f, p3 = 0.f;                           \
      _Pragma("unroll")                                                       \
      for (int nt = 0; nt < 4; ++nt) {                                        \
        f32x4 v = ACC[js][nt];                                                \
        p0 += fmaxf(v[0], 0.f) * w3[nt];                                      \
        p1 += fmaxf(v[1], 0.f) * w3[nt];                                      \
        p2 += fmaxf(v[2], 0.f) * w3[nt];                                      \
        p3 += fmaxf(v[3], 0.f) * w3[nt];                                      \
      }                                                                       \
      _Pragma("unroll")                                                       \
      for (int m = 1; m <= 8; m <<= 1) {                                      \
        p0 += __shfl_xor(p0, m, 64);                                          \
        p1 += __shfl_xor(p1, m, 64);                                          \
        p2 += __shfl_xor(p2, m, 64);                                          \
        p3 += __shfl_xor(p3, m, 64);                                          \
      }                                                                       \
      if (r == 0) {                                                           \
        int jb2 = j0 + js * 16 + 4 * g;                                       \
        int i = IVAR;                                                         \
        int j; float logit;                                                   \
        j = jb2 + 0;                                                          \
        if (j > i) {                                                          \
          logit = p0 * INV_SH + be3v;                                         \
          out[i * (NN - 1) - (i * (i - 1)) / 2 + (j - i - 1)] =               \
              1.0f / (1.0f + expf(-logit));                                   \
        }                                                                     \
        j = jb2 + 1;                                                          \
        if (j > i) {                                                          \
          logit = p1 * INV_SH + be3v;                                         \
          out[i * (NN - 1) - (i * (i - 1)) / 2 + (j - i - 1)] =               \
              1.0f / (1.0f + expf(-logit));                                   \
        }                                                                     \
        j = jb2 + 2;                                                          \
        if (j > i) {                                                          \
          logit = p2 * INV_SH + be3v;                                         \
          out[i * (NN - 1) - (i * (i - 1)) / 2 + (j - i - 1)] =               \
              1.0f / (1.0f + expf(-logit));                                   \
        }                                                                     \
        j = jb2 + 3;                                                          \
        if (j > i) {                                                          \
          logit = p3 * INV_SH + be3v;                                         \
          out[i * (NN - 1) - (i * (i - 1)) / 2 + (j - i - 1)] =               \
              1.0f / (1.0f + expf(-logit));                                   \
        }                                                                     \
      }                                                                       \
    }
    EPILOG(accA, iA)
    EPILOG(accB, iB)
#undef EPILOG
  }
}

extern "C" void kernel_launch(void* const* d_in, const int* in_sizes, int n_in,
                              void* d_out, int out_size, void* d_ws, size_t ws_size,
                              hipStream_t stream) {
  (void)in_sizes; (void)n_in; (void)out_size; (void)ws_size;
  const float* nf  = (const float*)d_in[0];
  const float* adj = (const float*)d_in[1];
  const float* W0  = (const float*)d_in[2];
  const float* b0  = (const float*)d_in[3];
  const float* W1  = (const float*)d_in[4];
  const float* b1  = (const float*)d_in[5];
  const float* W2  = (const float*)d_in[6];
  const float* b2  = (const float*)d_in[7];
  const float* We1 = (const float*)d_in[8];
  const float* be1 = (const float*)d_in[9];
  const float* We2 = (const float*)d_in[10];
  const float* be2 = (const float*)d_in[11];
  const float* We3 = (const float*)d_in[12];
  const float* be3 = (const float*)d_in[13];
  float* out = (float*)d_out;

  // Workspace layout (max 3584 KB, same proven footprint as round 4):
  //  [0,512K):    x0, later overwritten by x2 (x0 dead after layer 1)
  //  [512K,1024K): x1
  //  [1024K,1040K): Whg ; [1040K,1056K): Wlg
  //  [1536K,2560K): Ab ; [2560K,3584K): Bb
  char* ws = (char*)d_ws;
  float* x0 = (float*)(ws);
  float* x1 = (float*)(ws + (512 << 10));
  float* x2 = (float*)(ws);                        // reuse x0 slot
  _Float16* Whg = (_Float16*)(ws + (1024 << 10));  // 16 KB
  _Float16* Wlg = (_Float16*)(ws + (1040 << 10));  // 16 KB
  float* Ab = (float*)(ws + (1536 << 10));         // 1 MB (pre-scaled)
  float* Bb = (float*)(ws + (2560 << 10));         // 1 MB (pre-scaled)

  wsplit_kernel<<<32, 256, 0, stream>>>(We2, Whg, Wlg);
  gcn0_kernel<<<NN / 4, 256, 0, stream>>>(adj, nf, W0, b0, x0);
  gcnL_kernel<<<NN / 4, 256, 0, stream>>>(adj, x0, W1, b1, x1,
                                          nullptr, nullptr, nullptr, nullptr);
  gcnL_kernel<<<NN / 4, 256, 0, stream>>>(adj, x1, W2, b2, x2,
                                          We1, be1, Ab, Bb);
  pair_kernel<<<dim3(NN / 64, NN / 16), 256, 0, stream>>>(Ab, Bb, Whg, Wlg,
                                                          be2, We3, be3, out);
}